// Round 3
// baseline (121.213 us; speedup 1.0000x reference)
//
#include <hip/hip_runtime.h>
#include <hip/hip_bf16.h>
#include <stdint.h>
#include <stddef.h>

#define NS 8192
#define NT 8192
#define DD 512
#define INV_DNT (1.0f / ((float)DD * (float)NT))
#define INV_NT  (1.0f / (float)NT)

typedef __attribute__((ext_vector_type(8))) short short8;
typedef __attribute__((ext_vector_type(4))) float f32x4;

// ---- workspace layout (bytes) ----
#define WS_A    ((size_t)0)                    // NS*DD bf16
#define WS_B    (WS_A + (size_t)NS * DD * 2)   // NT*DD bf16
#define WS_SQS  (WS_B + (size_t)NT * DD * 2)   // NS f32 raw row sumsq
#define WS_SQT  (WS_SQS + (size_t)NS * 4)      // NT f32

__device__ __forceinline__ void gload16(const void* g, void* l) {
  __builtin_amdgcn_global_load_lds(
      (const __attribute__((address_space(1))) unsigned int*)g,
      (__attribute__((address_space(3))) unsigned int*)l, 16, 0, 0);
}

// ============================================================================
// prep: streaming fp32->bf16 convert + raw row sum-of-squares.
// ============================================================================
__global__ __launch_bounds__(256) void prep_kernel(
    const float* __restrict__ src, const float* __restrict__ tgt,
    char* __restrict__ ws) {
  const int tid = threadIdx.x, wid = tid >> 6, lane = tid & 63;
  __hip_bfloat16* Ab = (__hip_bfloat16*)(ws + WS_A);
  __hip_bfloat16* Bb = (__hip_bfloat16*)(ws + WS_B);
  float* sqs = (float*)(ws + WS_SQS);
  float* sqt = (float*)(ws + WS_SQT);

#pragma unroll
  for (int it = 0; it < 4; ++it) {
    const int row = blockIdx.x * 4 + wid + it * 4096;   // 0..16383
    const bool isT = row >= NS;
    const int r = isT ? row - NS : row;
    const float* in = (isT ? tgt : src) + (size_t)r * DD;
    const float4* rp = (const float4*)in;
    float4 v0 = rp[lane * 2], v1 = rp[lane * 2 + 1];
    float x[8] = {v0.x, v0.y, v0.z, v0.w, v1.x, v1.y, v1.z, v1.w};
    float ss = 0.f;
#pragma unroll
    for (int j = 0; j < 8; ++j) ss += x[j] * x[j];
    union { short8 s; __hip_bfloat16 h[8]; } u;
#pragma unroll
    for (int j = 0; j < 8; ++j) u.h[j] = __float2bfloat16(x[j]);
    *(short8*)((isT ? Bb : Ab) + (size_t)r * DD + lane * 8) = u.s;
#pragma unroll
    for (int off = 32; off >= 1; off >>= 1) ss += __shfl_xor(ss, off, 64);
    if (lane == 0) (isT ? sqt : sqs)[r] = ss;
  }
}

// ============================================================================
// gram: 256x256 tile, BK=64, 8 waves (2M x 4N), m201-style 4-phase/tile
// schedule: per phase {stage 1 half-tile; 12 ds_read; lgkm(0); 16 MFMA;
// vmcnt(8); barrier}.  Halves are interleaved: A-half = row bit6 parity,
// B-half = row bit5 parity, so phase (mh,nh) consumes exactly one A-half +
// one B-half.  Stage order per tile t: B1(t+1), A1(t+1), A0(t+2), B0(t+2).
// Involutive LDS swizzle: byte ^= ((row&7)<<4)  (mask from bits 7-9, XOR on
// bits 4-6) -> 2-way max on ds_read_b128.
// ============================================================================
__global__ __launch_bounds__(512, 2) void gram_kernel(
    const char* __restrict__ ws, const int* __restrict__ ssec,
    const int* __restrict__ tsec, float* __restrict__ out) {
  __shared__ __align__(16) char lds[2][65536];   // [buf][A 32KB | B 32KB]

  const float* sqs = (const float*)(ws + WS_SQS);
  const float* sqt = (const float*)(ws + WS_SQT);

  const int lin = blockIdx.x;
  const int wg = (lin & 7) * 128 + (lin >> 3);   // XCD-chunked (1024 % 8 == 0)
  const int m_blk = wg >> 5, n_blk = wg & 31;
  const int rowA = m_blk * 256, rowB = n_blk * 256;

  const int tid = threadIdx.x, wid = tid >> 6, lane = tid & 63;
  const int wrM = wid >> 2, wcN = wid & 3;
  const int q = lane & 15, h = lane >> 4;

  // ---- staging precompute. halves H: 0=A0,1=A1,2=B0,3=B1 (interleaved) ----
  const char* stSrc[4][2];
  int stDst[4][2];
#pragma unroll
  for (int H = 0; H < 4; ++H) {
#pragma unroll
    for (int i = 0; i < 2; ++i) {
      const int c = wid * 2 + i;               // chunk 0..15 (8 rows each)
      int rowstart;
      if (H < 2) rowstart = (c < 8) ? (H * 64 + c * 8) : (128 + H * 64 + (c - 8) * 8);
      else       rowstart = (H - 2) * 32 + (c >> 2) * 64 + (c & 3) * 8;
      const int dst = rowstart * 128;          // linear LDS, 128B rows
      const int o = dst + lane * 16;           // physical byte this lane fills
      const int l = o ^ (((o >> 7) & 7) << 4); // involution -> logical byte
      const int grow = l >> 7, gcol = l & 127;
      stDst[H][i] = dst;
      stSrc[H][i] = ws + ((H < 2) ? (WS_A + (size_t)(rowA + grow) * (DD * 2))
                                  : (WS_B + (size_t)(rowB + grow) * (DD * 2))) + gcol;
    }
  }

#define STG(H, T)                                                            \
  {                                                                          \
    char* _r = &lds[(T) & 1][(H) < 2 ? 0 : 32768];                           \
    gload16(stSrc[H][0] + (size_t)(T) * 128, _r + stDst[H][0]);              \
    gload16(stSrc[H][1] + (size_t)(T) * 128, _r + stDst[H][1]);              \
  }

  // ---- read-side fragment offsets (physical = logical ^ ((row&7)<<4)) ----
  const int swz = (q & 7) << 4;                 // row&7 == q&7 for frag rows
  const int colx0 = (h * 16) ^ swz;             // kk=0
  const int colx1 = (64 + h * 16) ^ swz;        // kk=1
  const int aBase = (wrM * 128 + q) * 128;
  const int bBase = (wcN * 64 + q) * 128;

  f32x4 acc[8][4];
#pragma unroll
  for (int mi = 0; mi < 8; ++mi)
#pragma unroll
    for (int ni = 0; ni < 4; ++ni) acc[mi][ni] = (f32x4){0.f, 0.f, 0.f, 0.f};

  // ---- prologue: issue order A0(0),B0(0),B1(0),A1(0),A0(1),B0(1) ----
  STG(0, 0) STG(2, 0) STG(3, 0) STG(1, 0) STG(0, 1) STG(2, 1)
  asm volatile("s_waitcnt vmcnt(8)" ::: "memory");   // A0(0),B0(0) landed
  __builtin_amdgcn_s_barrier();

#define VM8 asm volatile("s_waitcnt vmcnt(8)" ::: "memory")
#define VM4 asm volatile("s_waitcnt vmcnt(4)" ::: "memory")
#define VM2 asm volatile("s_waitcnt vmcnt(2)" ::: "memory")
#define VM0 asm volatile("s_waitcnt vmcnt(0)" ::: "memory")
#define VMNONE ((void)0)

#define PHASE(TC, MH, NH, DOST, STH, STT, VMC)                               \
  {                                                                          \
    if (DOST) STG(STH, STT)                                                  \
    const char* Ab = &lds[(TC) & 1][0];                                      \
    const char* Bb = &lds[(TC) & 1][32768];                                  \
    short8 af[4][2], bf[2][2];                                               \
    _Pragma("unroll") for (int mi = 0; mi < 4; ++mi) {                       \
      af[mi][0] = *(const short8*)(Ab + aBase + ((MH)*4 + mi) * 2048 + colx0);\
      af[mi][1] = *(const short8*)(Ab + aBase + ((MH)*4 + mi) * 2048 + colx1);\
    }                                                                        \
    _Pragma("unroll") for (int ni = 0; ni < 2; ++ni) {                       \
      bf[ni][0] = *(const short8*)(Bb + bBase + ((NH)*2 + ni) * 2048 + colx0);\
      bf[ni][1] = *(const short8*)(Bb + bBase + ((NH)*2 + ni) * 2048 + colx1);\
    }                                                                        \
    asm volatile("s_waitcnt lgkmcnt(0)" ::: "memory");                       \
    __builtin_amdgcn_sched_barrier(0);                                       \
    __builtin_amdgcn_s_setprio(1);                                           \
    _Pragma("unroll") for (int mi = 0; mi < 4; ++mi)                         \
      _Pragma("unroll") for (int ni = 0; ni < 2; ++ni) {                     \
        acc[(MH)*4+mi][(NH)*2+ni] = __builtin_amdgcn_mfma_f32_16x16x32_bf16( \
            af[mi][0], bf[ni][0], acc[(MH)*4+mi][(NH)*2+ni], 0, 0, 0);       \
        acc[(MH)*4+mi][(NH)*2+ni] = __builtin_amdgcn_mfma_f32_16x16x32_bf16( \
            af[mi][1], bf[ni][1], acc[(MH)*4+mi][(NH)*2+ni], 0, 0, 0);       \
      }                                                                      \
    __builtin_amdgcn_s_setprio(0);                                           \
    VMC;                                                                     \
    __builtin_amdgcn_s_barrier();                                            \
  }

  for (int t = 0; t < 6; ++t) {
    PHASE(t, 0, 0, true, 3, t + 1, VM8)   // reads A0,B0 ; stage B1(t+1)
    PHASE(t, 0, 1, true, 1, t + 1, VM8)   // reads A0,B1 ; stage A1(t+1)
    PHASE(t, 1, 0, true, 0, t + 2, VMNONE)// reads A1,B0 ; stage A0(t+2)
    PHASE(t, 1, 1, true, 2, t + 2, VM8)   // reads A1,B1 ; stage B0(t+2)
  }
  // t = 6 (stages for tile 8 suppressed; vmcnt relaxed accordingly)
  PHASE(6, 0, 0, true, 3, 7, VM8)
  PHASE(6, 0, 1, true, 1, 7, VM8)
  PHASE(6, 1, 0, false, 0, 0, VMNONE)
  PHASE(6, 1, 1, false, 0, 0, VM4)
  // t = 7 (drain 2 -> 0)
  PHASE(7, 0, 0, false, 0, 0, VM2)
  PHASE(7, 0, 1, false, 0, 0, VM0)
  PHASE(7, 1, 0, false, 0, 0, VMNONE)
  PHASE(7, 1, 1, false, 0, 0, VMNONE)
#undef PHASE
#undef STG

  // ---- epilogue: loss_s (same-sec sum of d2) + loss_c (hinge, rare) ----
  // C/D layout: col = q (target), row = h*4 + j (source)
  float sqc[4];
  int tc[4];
#pragma unroll
  for (int ni = 0; ni < 4; ++ni) {
    const int c = rowB + wcN * 64 + ni * 16 + q;
    sqc[ni] = sqt[c];
    tc[ni] = tsec[c];
  }
  const int rbase = rowA + wrM * 128;

  __syncthreads();                        // all tile reads done; reuse LDS
  float* lsr = (float*)&lds[0][0];        // [8 waves][4 h][32 (mi*4+j)]

#pragma unroll
  for (int mi = 0; mi < 8; ++mi) {
    const int r0 = rbase + mi * 16 + h * 4;
    const float4 s4 = *(const float4*)&sqs[r0];
    const int4 c4 = *(const int4*)&ssec[r0];
    const float sq4[4] = {s4.x, s4.y, s4.z, s4.w};
    const int sc4[4] = {c4.x, c4.y, c4.z, c4.w};
    float l[4] = {0.f, 0.f, 0.f, 0.f};
#pragma unroll
    for (int ni = 0; ni < 4; ++ni) {
#pragma unroll
      for (int j = 0; j < 4; ++j) {
        const float g = acc[mi][ni][j];
        const float d2r = sq4[j] + sqc[ni] - 2.f * g;
        if (sc4[j] == tc[ni]) {
          l[j] += fmaxf(d2r, 0.f);
        } else if (d2r < 128.f) {          // margin^2 * D; hinge (rare)
          const float d = sqrtf(fmaxf(d2r, 0.f) * (1.f / (float)DD));
          const float hh = 0.5f - d;
          atomicAdd(&out[NS + r0 + j], hh * hh * INV_NT);
        }
      }
    }
#pragma unroll
    for (int j = 0; j < 4; ++j) {
      float v = l[j];
      v += __shfl_xor(v, 1, 64);
      v += __shfl_xor(v, 2, 64);
      v += __shfl_xor(v, 4, 64);
      v += __shfl_xor(v, 8, 64);
      l[j] = v;
    }
    if (q < 4) {
      const float sv = (q == 0) ? l[0] : (q == 1) ? l[1] : (q == 2) ? l[2] : l[3];
      lsr[(wid * 4 + h) * 32 + mi * 4 + q] = sv;
    }
  }
  __syncthreads();

  // cross-wave (wcN) reduction: 256 rows, one atomic each
  if (tid < 256) {
    const int wrM_r = tid >> 7, within = tid & 127;
    const int mi = within >> 4, h_r = (within >> 2) & 3, j_r = within & 3;
    const int idx = mi * 4 + j_r;
    float v = lsr[((wrM_r * 4 + 0) * 4 + h_r) * 32 + idx] +
              lsr[((wrM_r * 4 + 1) * 4 + h_r) * 32 + idx] +
              lsr[((wrM_r * 4 + 2) * 4 + h_r) * 32 + idx] +
              lsr[((wrM_r * 4 + 3) * 4 + h_r) * 32 + idx];
    atomicAdd(&out[rowA + tid], v * INV_DNT);
  }
}

extern "C" void kernel_launch(void* const* d_in, const int* in_sizes, int n_in,
                              void* d_out, int out_size, void* d_ws, size_t ws_size,
                              hipStream_t stream) {
  const float* src = (const float*)d_in[0];
  const float* tgt = (const float*)d_in[1];
  const int* ssec = (const int*)d_in[2];
  const int* tsec = (const int*)d_in[3];
  float* out = (float*)d_out;
  char* ws = (char*)d_ws;

  hipMemsetAsync(out, 0, (size_t)2 * NS * sizeof(float), stream);
  prep_kernel<<<1024, 256, 0, stream>>>(src, tgt, ws);
  gram_kernel<<<1024, 512, 0, stream>>>(ws, ssec, tsec, out);
}

// Round 4
// 110.813 us; speedup vs baseline: 1.0939x; 1.0939x over previous
//
#include <hip/hip_runtime.h>
#include <hip/hip_bf16.h>
#include <stdint.h>
#include <stddef.h>

#define NS 8192
#define NT 8192
#define DD 512
#define INV_DNT (1.0f / ((float)DD * (float)NT))
#define INV_NT  (1.0f / (float)NT)

typedef __attribute__((ext_vector_type(8))) short short8;
typedef __attribute__((ext_vector_type(4))) float f32x4;

// ---- workspace layout (bytes) ----
#define WS_A    ((size_t)0)                    // NS*DD bf16
#define WS_B    (WS_A + (size_t)NS * DD * 2)   // NT*DD bf16
#define WS_SQS  (WS_B + (size_t)NT * DD * 2)   // NS f32 raw row sumsq
#define WS_SQT  (WS_SQS + (size_t)NS * 4)      // NT f32

__device__ __forceinline__ void gload16(const void* g, void* l) {
  __builtin_amdgcn_global_load_lds(
      (const __attribute__((address_space(1))) unsigned int*)g,
      (__attribute__((address_space(3))) unsigned int*)l, 16, 0, 0);
}

// ============================================================================
// prep: streaming fp32->bf16 convert + raw row sum-of-squares.
// ============================================================================
__global__ __launch_bounds__(256) void prep_kernel(
    const float* __restrict__ src, const float* __restrict__ tgt,
    char* __restrict__ ws) {
  const int tid = threadIdx.x, wid = tid >> 6, lane = tid & 63;
  __hip_bfloat16* Ab = (__hip_bfloat16*)(ws + WS_A);
  __hip_bfloat16* Bb = (__hip_bfloat16*)(ws + WS_B);
  float* sqs = (float*)(ws + WS_SQS);
  float* sqt = (float*)(ws + WS_SQT);

#pragma unroll
  for (int it = 0; it < 4; ++it) {
    const int row = blockIdx.x * 4 + wid + it * 4096;   // 0..16383
    const bool isT = row >= NS;
    const int r = isT ? row - NS : row;
    const float* in = (isT ? tgt : src) + (size_t)r * DD;
    const float4* rp = (const float4*)in;
    float4 v0 = rp[lane * 2], v1 = rp[lane * 2 + 1];
    float x[8] = {v0.x, v0.y, v0.z, v0.w, v1.x, v1.y, v1.z, v1.w};
    float ss = 0.f;
#pragma unroll
    for (int j = 0; j < 8; ++j) ss += x[j] * x[j];
    union { short8 s; __hip_bfloat16 h[8]; } u;
#pragma unroll
    for (int j = 0; j < 8; ++j) u.h[j] = __float2bfloat16(x[j]);
    *(short8*)((isT ? Bb : Ab) + (size_t)r * DD + lane * 8) = u.s;
#pragma unroll
    for (int off = 32; off >= 1; off >>= 1) ss += __shfl_xor(ss, off, 64);
    if (lane == 0) (isT ? sqt : sqs)[r] = ss;
  }
}

// ============================================================================
// gram: 256x256 tile, BK=64, 8 waves (2M x 4N).
// 4 phases/K-tile, sliced by (kk-half, m-half) for READ-MINIMAL LDS traffic
// (24 ds_read_b128 per wave per K-tile): B frags held in regs across the
// m-half pair of phases.  Staging: 8KB row-range units; schedule
// {Ph1:B23(t+1), Ph2:A02(t+1), Ph3:A13(t+1), Ph4:B01(t+2)}; gates VM4 at
// end-Ph1/end-Ph4 only (4-8 loads always in flight, distance 3-5 phases).
// Swizzle: physical byte = logical ^ ((row&7)<<4) (involution, rows 128B).
// ============================================================================
__global__ __launch_bounds__(512, 2) void gram_kernel(
    const char* __restrict__ ws, const int* __restrict__ ssec,
    const int* __restrict__ tsec, float* __restrict__ out) {
  __shared__ __align__(16) char lds[2][65536];   // [buf][A 32KB | B 32KB]

  const float* sqs = (const float*)(ws + WS_SQS);
  const float* sqt = (const float*)(ws + WS_SQT);

  // L2-friendly map: XCD x owns m_blks [4x,4x+4); within, 4m x 8n chunks
  // (A 1MB + B 2MB = 3MB < 4MB L2/XCD).
  const int lin = blockIdx.x;
  const int xcd = lin & 7, i = lin >> 3;
  const int nc = i >> 5, r_ = i & 31;
  const int m_blk = xcd * 4 + (r_ & 3);
  const int n_blk = nc * 8 + (r_ >> 2);
  const int rowA = m_blk * 256, rowB = n_blk * 256;

  const int tid = threadIdx.x, wid = tid >> 6, lane = tid & 63;
  const int wrM = wid >> 2, wcN = wid & 3;
  const int q = lane & 15, h = lane >> 4;

  // ---- staging: 8 units (u>>2: 0=A,1=B; u&3: 64-row range). 1 gload16/wave.
  const char* srcP[8];
  int dstO[8];
#pragma unroll
  for (int u = 0; u < 8; ++u) {
    const int X = u >> 2, ur = u & 3;
    const int dst = X * 32768 + (ur * 64 + wid * 8) * 128;  // wave-uniform
    dstO[u] = dst;
    const int po = (ur * 64 + wid * 8) * 128 + lane * 16;   // phys byte in region
    const int row_p = po >> 7;
    const int bl = (po & 127) ^ ((row_p & 7) << 4);         // logical byte in row
    srcP[u] = ws + (X ? WS_B : WS_A) +
              (size_t)((X ? rowB : rowA) + row_p) * (DD * 2) + bl;
  }

#define STG(u, T) gload16(srcP[u] + (size_t)(T) * 128, &lds[(T) & 1][dstO[u]]);

  // ---- read-side fragment offsets (physical = logical ^ ((row&7)<<4)) ----
  const int swz = (q & 7) << 4;
  const int colx[2] = {(h * 16) ^ swz, (64 + h * 16) ^ swz};
  const int aBase = (wrM * 128 + q) * 128;
  const int bBase = 32768 + (wcN * 64 + q) * 128;

  f32x4 acc[8][4];
#pragma unroll
  for (int mi = 0; mi < 8; ++mi)
#pragma unroll
    for (int ni = 0; ni < 4; ++ni) acc[mi][ni] = (f32x4){0.f, 0.f, 0.f, 0.f};

  short8 bf[4], af[4];

#define VM4 asm volatile("s_waitcnt vmcnt(4)" ::: "memory")
#define VM2 asm volatile("s_waitcnt vmcnt(2)" ::: "memory")
#define VM0 asm volatile("s_waitcnt vmcnt(0)" ::: "memory")
#define VMNONE ((void)0)

  // PHASE: optional stages; read af (4) [+ bf (4) if MH==0]; 16 MFMA.
#define PHASE(TC, KK, MH, STGBLK, VMC)                                        \
  {                                                                           \
    STGBLK;                                                                   \
    const char* Lb = &lds[(TC) & 1][0];                                       \
    if ((MH) == 0) {                                                          \
      _Pragma("unroll") for (int ni = 0; ni < 4; ++ni)                        \
          bf[ni] = *(const short8*)(Lb + bBase + ni * 2048 + colx[KK]);       \
    }                                                                         \
    _Pragma("unroll") for (int mi = 0; mi < 4; ++mi)                          \
        af[mi] = *(const short8*)(Lb + aBase + ((MH)*4 + mi) * 2048 + colx[KK]);\
    asm volatile("s_waitcnt lgkmcnt(0)" ::: "memory");                        \
    __builtin_amdgcn_sched_barrier(0);                                        \
    __builtin_amdgcn_s_setprio(1);                                            \
    _Pragma("unroll") for (int mi = 0; mi < 4; ++mi)                          \
      _Pragma("unroll") for (int ni = 0; ni < 4; ++ni)                        \
        acc[(MH)*4 + mi][ni] = __builtin_amdgcn_mfma_f32_16x16x32_bf16(       \
            af[mi], bf[ni], acc[(MH)*4 + mi][ni], 0, 0, 0);                   \
    __builtin_amdgcn_s_setprio(0);                                            \
    VMC;                                                                      \
    __builtin_amdgcn_s_barrier();                                             \
  }

  // ---- prologue: B(0) all, A02(0), A13(0), B01(1); retire first 6 ----
  STG(4, 0) STG(5, 0) STG(6, 0) STG(7, 0)
  STG(0, 0) STG(2, 0) STG(1, 0) STG(3, 0)
  STG(4, 1) STG(5, 1)
  VM4;
  __builtin_amdgcn_s_barrier();

#pragma unroll
  for (int t = 0; t < 6; ++t) {
    PHASE(t, 0, 0, { STG(6, t + 1) STG(7, t + 1) }, VM4)   // B23(t+1)
    PHASE(t, 0, 1, { STG(0, t + 1) STG(2, t + 1) }, VMNONE)// A02(t+1)
    PHASE(t, 1, 0, { STG(1, t + 1) STG(3, t + 1) }, VMNONE)// A13(t+1)
    PHASE(t, 1, 1, { STG(4, t + 2) STG(5, t + 2) }, VM4)   // B01(t+2)
  }
  // t = 6: last stages (units of tile 7); B01(8) suppressed
  PHASE(6, 0, 0, { STG(6, 7) STG(7, 7) }, VM4)
  PHASE(6, 0, 1, { STG(0, 7) STG(2, 7) }, VMNONE)
  PHASE(6, 1, 0, { STG(1, 7) STG(3, 7) }, VMNONE)
  PHASE(6, 1, 1, {}, VM2)
  // t = 7: drain
  PHASE(7, 0, 0, {}, VM0)
  PHASE(7, 0, 1, {}, VMNONE)
  PHASE(7, 1, 0, {}, VMNONE)
  PHASE(7, 1, 1, {}, VMNONE)
#undef PHASE
#undef STG

  // ---- epilogue: loss_s (same-sec sum of d2) + loss_c (hinge, rare) ----
  // C/D layout: col = q (target), row = h*4 + j (source)
  float sqc[4];
  int tc[4];
#pragma unroll
  for (int ni = 0; ni < 4; ++ni) {
    const int c = rowB + wcN * 64 + ni * 16 + q;
    sqc[ni] = sqt[c];
    tc[ni] = tsec[c];
  }
  const int rbase = rowA + wrM * 128;

  __syncthreads();                        // all tile reads done; reuse LDS
  float* lsr = (float*)&lds[0][0];        // [8 waves][4 h][32 (mi*4+j)]

#pragma unroll
  for (int mi = 0; mi < 8; ++mi) {
    const int r0 = rbase + mi * 16 + h * 4;
    const float4 s4 = *(const float4*)&sqs[r0];
    const int4 c4 = *(const int4*)&ssec[r0];
    const float sq4[4] = {s4.x, s4.y, s4.z, s4.w};
    const int sc4[4] = {c4.x, c4.y, c4.z, c4.w};
    float l[4] = {0.f, 0.f, 0.f, 0.f};
#pragma unroll
    for (int ni = 0; ni < 4; ++ni) {
#pragma unroll
      for (int j = 0; j < 4; ++j) {
        const float g = acc[mi][ni][j];
        const float d2r = sq4[j] + sqc[ni] - 2.f * g;
        if (sc4[j] == tc[ni]) {
          l[j] += fmaxf(d2r, 0.f);
        } else if (d2r < 128.f) {          // margin^2 * D; hinge (rare)
          const float d = sqrtf(fmaxf(d2r, 0.f) * (1.f / (float)DD));
          const float hh = 0.5f - d;
          atomicAdd(&out[NS + r0 + j], hh * hh * INV_NT);
        }
      }
    }
#pragma unroll
    for (int j = 0; j < 4; ++j) {
      float v = l[j];
      v += __shfl_xor(v, 1, 64);
      v += __shfl_xor(v, 2, 64);
      v += __shfl_xor(v, 4, 64);
      v += __shfl_xor(v, 8, 64);
      l[j] = v;
    }
    if (q < 4) {
      const float sv = (q == 0) ? l[0] : (q == 1) ? l[1] : (q == 2) ? l[2] : l[3];
      lsr[(wid * 4 + h) * 32 + mi * 4 + q] = sv;
    }
  }
  __syncthreads();

  // cross-wave (wcN) reduction: 256 rows, one atomic each
  if (tid < 256) {
    const int wrM_r = tid >> 7, within = tid & 127;
    const int mi = within >> 4, h_r = (within >> 2) & 3, j_r = within & 3;
    const int idx = mi * 4 + j_r;
    float v = lsr[((wrM_r * 4 + 0) * 4 + h_r) * 32 + idx] +
              lsr[((wrM_r * 4 + 1) * 4 + h_r) * 32 + idx] +
              lsr[((wrM_r * 4 + 2) * 4 + h_r) * 32 + idx] +
              lsr[((wrM_r * 4 + 3) * 4 + h_r) * 32 + idx];
    atomicAdd(&out[rowA + tid], v * INV_DNT);
  }
}

extern "C" void kernel_launch(void* const* d_in, const int* in_sizes, int n_in,
                              void* d_out, int out_size, void* d_ws, size_t ws_size,
                              hipStream_t stream) {
  const float* src = (const float*)d_in[0];
  const float* tgt = (const float*)d_in[1];
  const int* ssec = (const int*)d_in[2];
  const int* tsec = (const int*)d_in[3];
  float* out = (float*)d_out;
  char* ws = (char*)d_ws;

  hipMemsetAsync(out, 0, (size_t)2 * NS * sizeof(float), stream);
  prep_kernel<<<1024, 256, 0, stream>>>(src, tgt, ws);
  gram_kernel<<<1024, 512, 0, stream>>>(ws, ssec, tsec, out);
}